// Round 8
// baseline (135.316 us; speedup 1.0000x reference)
//
#include <hip/hip_runtime.h>

typedef short bf16x8 __attribute__((ext_vector_type(8)));
typedef float f32x4 __attribute__((ext_vector_type(4)));

__device__ __forceinline__ unsigned short f2bf(float f) {
  union { float f; unsigned int u; } v; v.f = f;
  unsigned int r = v.u + 0x7FFFu + ((v.u >> 16) & 1u);
  return (unsigned short)(r >> 16);
}

__device__ __forceinline__ bf16x8 cvt8(const float* __restrict__ p) {
  float4 a = *(const float4*)p;
  float4 b = *(const float4*)(p + 4);
  bf16x8 r;
  r[0] = f2bf(a.x); r[1] = f2bf(a.y); r[2] = f2bf(a.z); r[3] = f2bf(a.w);
  r[4] = f2bf(b.x); r[5] = f2bf(b.y); r[6] = f2bf(b.z); r[7] = f2bf(b.w);
  return r;
}

// ---- QKV GEMM, split-K x4, inline fp32->bf16 cast.
// Q,K -> QKb[512][384] (row layout). V -> Vt[768][512] (transposed, t-contig).
__global__ __launch_bounds__(256) void gemm_qkv(
    const float* __restrict__ hs, const float* __restrict__ Wq,
    const float* __restrict__ Wk, const float* __restrict__ Wv,
    unsigned short* __restrict__ QKb, unsigned short* __restrict__ Vt) {
  __shared__ f32x4 part[4][64];
  const int tid = threadIdx.x;
  const int w = tid >> 6, lane = tid & 63;
  const int lm = lane & 15, quad = lane >> 4;
  const int mt = blockIdx.y * 16;
  const int n0 = blockIdx.x * 16;
  const float* B; int bn;
  if (n0 < 192)      { B = Wq; bn = n0; }
  else if (n0 < 384) { B = Wk; bn = n0 - 192; }
  else               { B = Wv; bn = n0 - 384; }
  const int kw = w * 192;
  const float* a_ptr = hs + (mt + lm) * 768 + kw + quad * 8;
  const float* b_ptr = B + (bn + lm) * 768 + kw + quad * 8;
  f32x4 acc = {0.f, 0.f, 0.f, 0.f};
#pragma unroll
  for (int kb = 0; kb < 192; kb += 32) {
    bf16x8 av = cvt8(a_ptr + kb);
    bf16x8 bv = cvt8(b_ptr + kb);
    acc = __builtin_amdgcn_mfma_f32_16x16x32_bf16(av, bv, acc, 0, 0, 0);
  }
  part[w][lane] = acc;
  __syncthreads();
  if (w == 0) {
    f32x4 s = part[0][lane] + part[1][lane] + part[2][lane] + part[3][lane];
    if (n0 < 384) {
#pragma unroll
      for (int r = 0; r < 4; ++r)
        QKb[(mt + quad * 4 + r) * 384 + n0 + lm] = f2bf(s[r]);
    } else {
      ushort4 o;
      o.x = f2bf(s[0]); o.y = f2bf(s[1]); o.z = f2bf(s[2]); o.w = f2bf(s[3]);
      *(ushort4*)&Vt[(n0 - 384 + lm) * 512 + mt + quad * 4] = o;
    }
  }
}

// ---- causal taylor attention, no atomics, no block barriers.
// grid (c=8, h=12, parity=2); block handles s-blocks sb = parity, parity+2, ... <= c.
__global__ __launch_bounds__(256) void attn(
    const unsigned short* __restrict__ QKb, const unsigned short* __restrict__ Vt,
    float* __restrict__ numP, float* __restrict__ denP) {
  const int c = blockIdx.x, h = blockIdx.y, half = blockIdx.z;
  const int tid = threadIdx.x;
  const int w = tid >> 6, lane = tid & 63;
  const int lm = lane & 15, quad = lane >> 4;
  __shared__ __align__(16) unsigned short scl[2][64 * 72];
  const int t0 = c * 64;
  bf16x8 aq = {0, 0, 0, 0, 0, 0, 0, 0};
  if (quad < 2)
    aq = *(const bf16x8*)&QKb[(t0 + w * 16 + lm) * 384 + h * 16 + quad * 8];
  f32x4 av[4] = {{0.f,0.f,0.f,0.f},{0.f,0.f,0.f,0.f},{0.f,0.f,0.f,0.f},{0.f,0.f,0.f,0.f}};
  float dsum[4] = {0.f, 0.f, 0.f, 0.f};
  const unsigned short* vbase = Vt + (h * 64 + lm) * 512;
  for (int sb = half; sb <= c; sb += 2) {
    const int s0 = sb * 64;
    f32x4 qk[4];
#pragma unroll
    for (int sbt = 0; sbt < 4; ++sbt) {
      bf16x8 bk = {0, 0, 0, 0, 0, 0, 0, 0};
      if (quad < 2)
        bk = *(const bf16x8*)&QKb[(s0 + sbt * 16 + lm) * 384 + 192 + h * 16 + quad * 8];
      f32x4 z = {0.f, 0.f, 0.f, 0.f};
      qk[sbt] = __builtin_amdgcn_mfma_f32_16x16x32_bf16(aq, bk, z, 0, 0, 0);
    }
    unsigned short* sw = &scl[sb & 1][0];
#pragma unroll
    for (int sbt = 0; sbt < 4; ++sbt) {
#pragma unroll
      for (int r = 0; r < 4; ++r) {
        int tl = w * 16 + quad * 4 + r;
        int sl = sbt * 16 + lm;
        float x = qk[sbt][r];
        float val = (s0 + sl <= t0 + tl) ? 1.f + 0.25f * x + 0.03125f * x * x : 0.f;
        dsum[r] += val;
        sw[tl * 72 + sl] = f2bf(val);
      }
    }
    // AV: wave-private rows of sw; B-fragments straight from global Vt.
#pragma unroll
    for (int kb = 0; kb < 2; ++kb) {
      bf16x8 a = *(const bf16x8*)&sw[(w * 16 + lm) * 72 + kb * 32 + quad * 8];
#pragma unroll
      for (int dt = 0; dt < 4; ++dt) {
        bf16x8 b = *(const bf16x8*)&vbase[dt * 16 * 512 + s0 + kb * 32 + quad * 8];
        av[dt] = __builtin_amdgcn_mfma_f32_16x16x32_bf16(a, b, av[dt], 0, 0, 0);
      }
    }
  }
#pragma unroll
  for (int r = 0; r < 4; ++r) {
    float v = dsum[r];
    v += __shfl_xor(v, 1); v += __shfl_xor(v, 2);
    v += __shfl_xor(v, 4); v += __shfl_xor(v, 8);
    if (lm == 0) denP[half * 6144 + (t0 + w * 16 + quad * 4 + r) * 12 + h] = v;
  }
  float* np = numP + half * 393216;
#pragma unroll
  for (int dt = 0; dt < 4; ++dt)
#pragma unroll
    for (int r = 0; r < 4; ++r)
      np[(t0 + w * 16 + quad * 4 + r) * 768 + h * 64 + dt * 16 + lm] = av[dt][r];
}

// ---- out GEMM, split-K x4: out = ((num0+num1)/(den0+den1+eps)) @ Wo^T ----
__global__ __launch_bounds__(256) void gemm_out(
    const float* __restrict__ numP, const float* __restrict__ denP,
    const float* __restrict__ Wo, float* __restrict__ out) {
  __shared__ f32x4 part[4][64];
  const int tid = threadIdx.x;
  const int w = tid >> 6, lane = tid & 63;
  const int lm = lane & 15, quad = lane >> 4;
  const int mt = blockIdx.y * 16;
  const int nt = blockIdx.x * 16;
  const int t = mt + lm;
  const int kw = w * 192;
  f32x4 acc = {0.f, 0.f, 0.f, 0.f};
#pragma unroll
  for (int kb = 0; kb < 192; kb += 32) {
    int k0 = kw + kb + quad * 8;
    int hh = k0 >> 6;
    float den = denP[t * 12 + hh] + denP[6144 + t * 12 + hh] + 1e-12f;
    float inv = 1.f / den;
    const float* n0p = numP + t * 768 + k0;
    const float* n1p = numP + 393216 + t * 768 + k0;
    float4 x0 = *(const float4*)n0p, x1 = *(const float4*)(n0p + 4);
    float4 y0 = *(const float4*)n1p, y1 = *(const float4*)(n1p + 4);
    bf16x8 a;
    a[0] = f2bf((x0.x + y0.x) * inv); a[1] = f2bf((x0.y + y0.y) * inv);
    a[2] = f2bf((x0.z + y0.z) * inv); a[3] = f2bf((x0.w + y0.w) * inv);
    a[4] = f2bf((x1.x + y1.x) * inv); a[5] = f2bf((x1.y + y1.y) * inv);
    a[6] = f2bf((x1.z + y1.z) * inv); a[7] = f2bf((x1.w + y1.w) * inv);
    bf16x8 bv = cvt8(Wo + (nt + lm) * 768 + k0);
    acc = __builtin_amdgcn_mfma_f32_16x16x32_bf16(a, bv, acc, 0, 0, 0);
  }
  part[w][lane] = acc;
  __syncthreads();
  if (w == 0) {
    f32x4 s = part[0][lane] + part[1][lane] + part[2][lane] + part[3][lane];
#pragma unroll
    for (int r = 0; r < 4; ++r)
      out[(mt + quad * 4 + r) * 768 + nt + lm] = s[r];
  }
}

extern "C" void kernel_launch(void* const* d_in, const int* in_sizes, int n_in,
                              void* d_out, int out_size, void* d_ws, size_t ws_size,
                              hipStream_t stream) {
  const float* hs = (const float*)d_in[0];
  const float* Wq = (const float*)d_in[1];
  const float* Wk = (const float*)d_in[2];
  const float* Wv = (const float*)d_in[3];
  const float* Wo = (const float*)d_in[4];
  float* out = (float*)d_out;
  float* ws = (float*)d_ws;

  float* numP = ws;                                      // 2*512*768 = 786432 f
  float* denP = ws + 786432;                             // 2*512*12  = 12288 f
  unsigned short* QKb = (unsigned short*)(ws + 798720);  // 512*384 us
  unsigned short* Vt  = QKb + 196608;                    // 768*512 us

  // QKV projections (inline cast); V emitted transposed
  gemm_qkv<<<dim3(72, 32), 256, 0, stream>>>(hs, Wq, Wk, Wv, QKb, Vt);
  // causal taylor attention partials (parity-split, no atomics)
  attn<<<dim3(8, 12, 2), 256, 0, stream>>>(QKb, Vt, numP, denP);
  // out = (num/den) @ Wo^T (inline cast of Wo)
  gemm_out<<<dim3(48, 32), 256, 0, stream>>>(numP, denP, Wo, out);
}

// Round 9
// 119.499 us; speedup vs baseline: 1.1324x; 1.1324x over previous
//
#include <hip/hip_runtime.h>

typedef short bf16x8 __attribute__((ext_vector_type(8)));
typedef float f32x4 __attribute__((ext_vector_type(4)));

__device__ __forceinline__ unsigned short f2bf(float f) {
  union { float f; unsigned int u; } v; v.f = f;
  unsigned int r = v.u + 0x7FFFu + ((v.u >> 16) & 1u);
  return (unsigned short)(r >> 16);
}

// ---- one-pass fp32->bf16 cast: hs, Wq|Wk|Wv (concat), Wo ----
__global__ __launch_bounds__(256) void prep(
    const float* __restrict__ hs, const float* __restrict__ Wq,
    const float* __restrict__ Wk, const float* __restrict__ Wv,
    const float* __restrict__ Wo, unsigned short* __restrict__ hsb,
    unsigned short* __restrict__ Wqkvb, unsigned short* __restrict__ Wob) {
  int b = blockIdx.x;
  const float* src; unsigned short* dst; int base;
  if (b < 384)       { src = hs; dst = hsb;            base = b * 1024; }
  else if (b < 528)  { src = Wq; dst = Wqkvb;          base = (b - 384) * 1024; }
  else if (b < 672)  { src = Wk; dst = Wqkvb + 147456; base = (b - 528) * 1024; }
  else if (b < 1248) { src = Wv; dst = Wqkvb + 294912; base = (b - 672) * 1024; }
  else               { src = Wo; dst = Wob;            base = (b - 1248) * 1024; }
  int i = base + threadIdx.x * 4;
  float4 x = *(const float4*)&src[i];
  ushort4 o;
  o.x = f2bf(x.x); o.y = f2bf(x.y); o.z = f2bf(x.z); o.w = f2bf(x.w);
  *(ushort4*)&dst[i] = o;
}

// ---- QKV GEMM, split-K x4, bf16 in. Q,K -> QKb[512][384]; V -> Vt[768][512] ----
__global__ __launch_bounds__(256) void gemm_qkv(
    const unsigned short* __restrict__ A, const unsigned short* __restrict__ B,
    unsigned short* __restrict__ QKb, unsigned short* __restrict__ Vt) {
  __shared__ f32x4 part[4][64];
  const int tid = threadIdx.x;
  const int w = tid >> 6, lane = tid & 63;
  const int lm = lane & 15, quad = lane >> 4;
  const int mt = blockIdx.y * 16;
  const int n0 = blockIdx.x * 16;
  const int kw = w * 192;
  const unsigned short* a_ptr = A + (mt + lm) * 768 + kw + quad * 8;
  const unsigned short* b_ptr = B + (n0 + lm) * 768 + kw + quad * 8;
  f32x4 acc = {0.f, 0.f, 0.f, 0.f};
#pragma unroll
  for (int kb = 0; kb < 192; kb += 32) {
    bf16x8 av = *(const bf16x8*)(a_ptr + kb);
    bf16x8 bv = *(const bf16x8*)(b_ptr + kb);
    acc = __builtin_amdgcn_mfma_f32_16x16x32_bf16(av, bv, acc, 0, 0, 0);
  }
  part[w][lane] = acc;
  __syncthreads();
  if (w == 0) {
    f32x4 s = part[0][lane] + part[1][lane] + part[2][lane] + part[3][lane];
    if (n0 < 384) {
#pragma unroll
      for (int r = 0; r < 4; ++r)
        QKb[(mt + quad * 4 + r) * 384 + n0 + lm] = f2bf(s[r]);
    } else {
      ushort4 o;
      o.x = f2bf(s[0]); o.y = f2bf(s[1]); o.z = f2bf(s[2]); o.w = f2bf(s[3]);
      *(ushort4*)&Vt[(n0 - 384 + lm) * 512 + mt + quad * 4] = o;
    }
  }
}

// ---- causal taylor attention, no atomics, no block barriers.
// grid (c=8, h=12, parity=2); block handles s-blocks sb = parity, parity+2, ... <= c.
__global__ __launch_bounds__(256) void attn(
    const unsigned short* __restrict__ QKb, const unsigned short* __restrict__ Vt,
    float* __restrict__ numP, float* __restrict__ denP) {
  const int c = blockIdx.x, h = blockIdx.y, half = blockIdx.z;
  const int tid = threadIdx.x;
  const int w = tid >> 6, lane = tid & 63;
  const int lm = lane & 15, quad = lane >> 4;
  __shared__ __align__(16) unsigned short scl[2][64 * 72];
  const int t0 = c * 64;
  bf16x8 aq = {0, 0, 0, 0, 0, 0, 0, 0};
  if (quad < 2)
    aq = *(const bf16x8*)&QKb[(t0 + w * 16 + lm) * 384 + h * 16 + quad * 8];
  f32x4 av[4] = {{0.f,0.f,0.f,0.f},{0.f,0.f,0.f,0.f},{0.f,0.f,0.f,0.f},{0.f,0.f,0.f,0.f}};
  float dsum[4] = {0.f, 0.f, 0.f, 0.f};
  const unsigned short* vbase = Vt + (h * 64 + lm) * 512;
  for (int sb = half; sb <= c; sb += 2) {
    const int s0 = sb * 64;
    f32x4 qk[4];
#pragma unroll
    for (int sbt = 0; sbt < 4; ++sbt) {
      bf16x8 bk = {0, 0, 0, 0, 0, 0, 0, 0};
      if (quad < 2)
        bk = *(const bf16x8*)&QKb[(s0 + sbt * 16 + lm) * 384 + 192 + h * 16 + quad * 8];
      f32x4 z = {0.f, 0.f, 0.f, 0.f};
      qk[sbt] = __builtin_amdgcn_mfma_f32_16x16x32_bf16(aq, bk, z, 0, 0, 0);
    }
    unsigned short* sw = &scl[sb & 1][0];
#pragma unroll
    for (int sbt = 0; sbt < 4; ++sbt) {
#pragma unroll
      for (int r = 0; r < 4; ++r) {
        int tl = w * 16 + quad * 4 + r;
        int sl = sbt * 16 + lm;
        float x = qk[sbt][r];
        float val = (s0 + sl <= t0 + tl) ? 1.f + 0.25f * x + 0.03125f * x * x : 0.f;
        dsum[r] += val;
        sw[tl * 72 + sl] = f2bf(val);
      }
    }
    // AV: wave-private rows of sw; B-fragments straight from global Vt.
#pragma unroll
    for (int kb = 0; kb < 2; ++kb) {
      bf16x8 a = *(const bf16x8*)&sw[(w * 16 + lm) * 72 + kb * 32 + quad * 8];
#pragma unroll
      for (int dt = 0; dt < 4; ++dt) {
        bf16x8 b = *(const bf16x8*)&vbase[dt * 16 * 512 + s0 + kb * 32 + quad * 8];
        av[dt] = __builtin_amdgcn_mfma_f32_16x16x32_bf16(a, b, av[dt], 0, 0, 0);
      }
    }
  }
#pragma unroll
  for (int r = 0; r < 4; ++r) {
    float v = dsum[r];
    v += __shfl_xor(v, 1); v += __shfl_xor(v, 2);
    v += __shfl_xor(v, 4); v += __shfl_xor(v, 8);
    if (lm == 0) denP[half * 6144 + (t0 + w * 16 + quad * 4 + r) * 12 + h] = v;
  }
  float* np = numP + half * 393216;
#pragma unroll
  for (int dt = 0; dt < 4; ++dt)
#pragma unroll
    for (int r = 0; r < 4; ++r)
      np[(t0 + w * 16 + quad * 4 + r) * 768 + h * 64 + dt * 16 + lm] = av[dt][r];
}

// ---- out GEMM, split-K x4: out = ((num0+num1)/(den0+den1+eps)) @ Wo^T ----
__global__ __launch_bounds__(256) void gemm_out(
    const float* __restrict__ numP, const float* __restrict__ denP,
    const unsigned short* __restrict__ Wob, float* __restrict__ out) {
  __shared__ f32x4 part[4][64];
  const int tid = threadIdx.x;
  const int w = tid >> 6, lane = tid & 63;
  const int lm = lane & 15, quad = lane >> 4;
  const int mt = blockIdx.y * 16;
  const int nt = blockIdx.x * 16;
  const int t = mt + lm;
  const int kw = w * 192;
  f32x4 acc = {0.f, 0.f, 0.f, 0.f};
#pragma unroll
  for (int kb = 0; kb < 192; kb += 32) {
    int k0 = kw + kb + quad * 8;
    int hh = k0 >> 6;
    float den = denP[t * 12 + hh] + denP[6144 + t * 12 + hh] + 1e-12f;
    float inv = 1.f / den;
    const float* n0p = numP + t * 768 + k0;
    const float* n1p = numP + 393216 + t * 768 + k0;
    float4 x0 = *(const float4*)n0p, x1 = *(const float4*)(n0p + 4);
    float4 y0 = *(const float4*)n1p, y1 = *(const float4*)(n1p + 4);
    bf16x8 a;
    a[0] = f2bf((x0.x + y0.x) * inv); a[1] = f2bf((x0.y + y0.y) * inv);
    a[2] = f2bf((x0.z + y0.z) * inv); a[3] = f2bf((x0.w + y0.w) * inv);
    a[4] = f2bf((x1.x + y1.x) * inv); a[5] = f2bf((x1.y + y1.y) * inv);
    a[6] = f2bf((x1.z + y1.z) * inv); a[7] = f2bf((x1.w + y1.w) * inv);
    bf16x8 bv = *(const bf16x8*)&Wob[(nt + lm) * 768 + k0];
    acc = __builtin_amdgcn_mfma_f32_16x16x32_bf16(a, bv, acc, 0, 0, 0);
  }
  part[w][lane] = acc;
  __syncthreads();
  if (w == 0) {
    f32x4 s = part[0][lane] + part[1][lane] + part[2][lane] + part[3][lane];
#pragma unroll
    for (int r = 0; r < 4; ++r)
      out[(mt + quad * 4 + r) * 768 + nt + lm] = s[r];
  }
}

extern "C" void kernel_launch(void* const* d_in, const int* in_sizes, int n_in,
                              void* d_out, int out_size, void* d_ws, size_t ws_size,
                              hipStream_t stream) {
  const float* hs = (const float*)d_in[0];
  const float* Wq = (const float*)d_in[1];
  const float* Wk = (const float*)d_in[2];
  const float* Wv = (const float*)d_in[3];
  const float* Wo = (const float*)d_in[4];
  float* out = (float*)d_out;
  float* ws = (float*)d_ws;

  float* numP = ws;                                      // 2*512*768 = 786432 f
  float* denP = ws + 786432;                             // 2*512*12  = 12288 f
  unsigned short* hsb   = (unsigned short*)(ws + 798720);  // 393216 us
  unsigned short* Wqkvb = hsb + 393216;                    // 884736 us
  unsigned short* Wob   = Wqkvb + 884736;                  // 589824 us
  unsigned short* QKb   = Wob + 589824;                    // 196608 us
  unsigned short* Vt    = QKb + 196608;                    // 393216 us

  // one-pass casts
  prep<<<dim3(1824), 256, 0, stream>>>(hs, Wq, Wk, Wv, Wo, hsb, Wqkvb, Wob);
  // QKV projections; V emitted transposed
  gemm_qkv<<<dim3(72, 32), 256, 0, stream>>>(hsb, Wqkvb, QKb, Vt);
  // causal taylor attention partials (parity-split, no atomics)
  attn<<<dim3(8, 12, 2), 256, 0, stream>>>(QKb, Vt, numP, denP);
  // out = (num/den) @ Wo^T
  gemm_out<<<dim3(48, 32), 256, 0, stream>>>(numP, denP, Wob, out);
}